// Round 1
// baseline (8466.058 us; speedup 1.0000x reference)
//
#include <hip/hip_runtime.h>

// GCN 3-layer, N=100000, E=1600000, D=128.
// Pipeline per layer L:
//   gemm_g: bufA = bufB = g = dinv[i] * (f(in) @ W)   (f = prev-layer epilogue: relu(dinv*v+b), identity for L=1)
//   scatter: bufB[dst] += bufA[src]                    (pure add; dinv folded into g)
// Final: out[c] = mean_i relu(dinv[i]*bufB[i][c] + b3[c])

__global__ __launch_bounds__(256) void count_deg_k(const int* __restrict__ ei,
                                                   float* __restrict__ deg, int e) {
  int t = blockIdx.x * 256 + threadIdx.x;
  if (t < e) unsafeAtomicAdd(&deg[ei[e + t]], 1.0f);  // dst indices live at ei[E..2E)
}

__global__ __launch_bounds__(256) void dinv_k(float* deg, int n) {
  int t = blockIdx.x * 256 + threadIdx.x;
  if (t < n) deg[t] = 1.0f / sqrtf(deg[t] + 1.0f);
}

// 64 rows x 128 cols per block, 256 threads, thread tile 4 rows x 8 cols.
// s_in: 64x128 padded to 132 floats/row (33 float4) -> 2-way bank alias (free).
// W staged in LDS in two 64-row halves (32KB each live region reused).
template <int EPI>
__global__ __launch_bounds__(256) void gemm_g(
    const float* in, const float* __restrict__ W,
    const float* __restrict__ dinv, const float* __restrict__ bias,
    float* __restrict__ outA, float* outB, int n)
{
  __shared__ float s_in[64 * 33 * 4];   // 64 rows x 132 floats
  __shared__ float s_w[64 * 128];       // one K-half of W
  float4* s_in4 = (float4*)s_in;
  float4* s_w4  = (float4*)s_w;
  const int t = threadIdx.x;
  const int row0 = blockIdx.x * 64;

  // ---- stage input tile (apply previous layer's epilogue once, here) ----
  const float4* in4 = (const float4*)in;
  #pragma unroll
  for (int j = 0; j < 8; ++j) {
    int f = t + j * 256;          // 0..2047 over 64 rows x 32 float4
    int r = f >> 5, c4 = f & 31;
    int row = row0 + r;
    float4 v = make_float4(0.f, 0.f, 0.f, 0.f);
    if (row < n) {
      v = in4[(size_t)row * 32 + c4];
      if (EPI) {
        float dv = dinv[row];
        float4 bb = ((const float4*)bias)[c4];
        v.x = fmaxf(fmaf(dv, v.x, bb.x), 0.f);
        v.y = fmaxf(fmaf(dv, v.y, bb.y), 0.f);
        v.z = fmaxf(fmaf(dv, v.z, bb.z), 0.f);
        v.w = fmaxf(fmaf(dv, v.w, bb.w), 0.f);
      }
    }
    s_in4[r * 33 + c4] = v;
  }

  float acc[4][8];
  #pragma unroll
  for (int i = 0; i < 4; ++i)
    #pragma unroll
    for (int j = 0; j < 8; ++j) acc[i][j] = 0.f;

  const int rg = t >> 4;   // 16 row-groups of 4 rows
  const int cg = t & 15;   // 16 col-groups of 8 cols

  const float4* W4 = (const float4*)W;
  #pragma unroll
  for (int half = 0; half < 2; ++half) {
    __syncthreads();  // s_in staged (half 0) / previous half's reads done (half 1)
    #pragma unroll
    for (int j = 0; j < 8; ++j) {
      int f = t + j * 256;        // 64 W-rows x 32 float4
      s_w4[f] = W4[half * 2048 + f];
    }
    __syncthreads();
    for (int k4 = 0; k4 < 16; ++k4) {
      float a[4][4];
      #pragma unroll
      for (int i = 0; i < 4; ++i)
        *(float4*)a[i] = s_in4[(rg * 4 + i) * 33 + half * 16 + k4];
      #pragma unroll
      for (int kk = 0; kk < 4; ++kk) {
        float4 w0 = s_w4[(k4 * 4 + kk) * 32 + cg * 2];
        float4 w1 = s_w4[(k4 * 4 + kk) * 32 + cg * 2 + 1];
        #pragma unroll
        for (int i = 0; i < 4; ++i) {
          float av = a[i][kk];
          acc[i][0] = fmaf(av, w0.x, acc[i][0]);
          acc[i][1] = fmaf(av, w0.y, acc[i][1]);
          acc[i][2] = fmaf(av, w0.z, acc[i][2]);
          acc[i][3] = fmaf(av, w0.w, acc[i][3]);
          acc[i][4] = fmaf(av, w1.x, acc[i][4]);
          acc[i][5] = fmaf(av, w1.y, acc[i][5]);
          acc[i][6] = fmaf(av, w1.z, acc[i][6]);
          acc[i][7] = fmaf(av, w1.w, acc[i][7]);
        }
      }
    }
  }

  // ---- epilogue: g = dinv[row] * acc -> outA (gather buf) and outB (accum init) ----
  #pragma unroll
  for (int i = 0; i < 4; ++i) {
    int row = row0 + rg * 4 + i;
    if (row < n) {
      float dv = dinv[row];
      float4 o0, o1;
      o0.x = acc[i][0] * dv; o0.y = acc[i][1] * dv;
      o0.z = acc[i][2] * dv; o0.w = acc[i][3] * dv;
      o1.x = acc[i][4] * dv; o1.y = acc[i][5] * dv;
      o1.z = acc[i][6] * dv; o1.w = acc[i][7] * dv;
      size_t base = (size_t)row * 32 + cg * 2;
      ((float4*)outA)[base]     = o0;
      ((float4*)outA)[base + 1] = o1;
      ((float4*)outB)[base]     = o0;
      ((float4*)outB)[base + 1] = o1;
    }
  }
}

// One 32-lane half-wave per edge; each lane handles one float4 (4 atomics).
__global__ __launch_bounds__(256) void scatter_k(const float* __restrict__ A,
                                                 float* __restrict__ B,
                                                 const int* __restrict__ ei, int e) {
  int g = blockIdx.x * 256 + threadIdx.x;
  int edge = g >> 5;
  int l = g & 31;
  if (edge >= e) return;
  int s = ei[edge];
  int d = ei[e + edge];
  float4 v = ((const float4*)A)[(size_t)s * 32 + l];
  float* bp = B + (size_t)d * 128 + l * 4;
  unsafeAtomicAdd(bp + 0, v.x);
  unsafeAtomicAdd(bp + 1, v.y);
  unsafeAtomicAdd(bp + 2, v.z);
  unsafeAtomicAdd(bp + 3, v.w);
}

__global__ __launch_bounds__(128) void mean_k(const float* __restrict__ B,
                                              const float* __restrict__ dinv,
                                              const float* __restrict__ bias,
                                              float* __restrict__ out, int n, float invn) {
  int c = threadIdx.x;
  float bb = bias[c];
  float sum = 0.f;
  for (int row = blockIdx.x; row < n; row += gridDim.x) {
    float v = fmaf(dinv[row], B[(size_t)row * 128 + c], bb);
    sum += fmaxf(v, 0.f);
  }
  unsafeAtomicAdd(&out[c], sum * invn);
}

extern "C" void kernel_launch(void* const* d_in, const int* in_sizes, int n_in,
                              void* d_out, int out_size, void* d_ws, size_t ws_size,
                              hipStream_t stream) {
  const float* x  = (const float*)d_in[0];
  const int*   ei = (const int*)d_in[1];
  const float* W1 = (const float*)d_in[2];
  const float* b1 = (const float*)d_in[3];
  const float* W2 = (const float*)d_in[4];
  const float* b2 = (const float*)d_in[5];
  const float* W3 = (const float*)d_in[6];
  const float* b3 = (const float*)d_in[7];
  float* out = (float*)d_out;

  const int n = in_sizes[0] / 128;
  const int e = in_sizes[1] / 2;

  char* wsc = (char*)d_ws;
  float* dinv = (float*)wsc;                          // n floats (deg -> dinv in place)
  float* bufA = (float*)(wsc + (1 << 19));            // n*128 floats (g, gather source)
  float* bufB = bufA + (size_t)n * 128;               // n*128 floats (accumulator)

  hipMemsetAsync(dinv, 0, (size_t)n * sizeof(float), stream);
  count_deg_k<<<(e + 255) / 256, 256, 0, stream>>>(ei, dinv, e);
  dinv_k<<<(n + 255) / 256, 256, 0, stream>>>(dinv, n);

  const int gb = (n + 63) / 64;
  const int sb = (e * 32 + 255) / 256;

  gemm_g<0><<<gb, 256, 0, stream>>>(x,    W1, dinv, nullptr, bufA, bufB, n);
  scatter_k<<<sb, 256, 0, stream>>>(bufA, bufB, ei, e);
  gemm_g<1><<<gb, 256, 0, stream>>>(bufB, W2, dinv, b1, bufA, bufB, n);
  scatter_k<<<sb, 256, 0, stream>>>(bufA, bufB, ei, e);
  gemm_g<1><<<gb, 256, 0, stream>>>(bufB, W3, dinv, b2, bufA, bufB, n);
  scatter_k<<<sb, 256, 0, stream>>>(bufA, bufB, ei, e);

  hipMemsetAsync(out, 0, 128 * sizeof(float), stream);
  mean_k<<<2048, 128, 0, stream>>>(bufB, dinv, b3, out, n, 1.0f / (float)n);
}

// Round 2
// 862.860 us; speedup vs baseline: 9.8116x; 9.8116x over previous
//
#include <hip/hip_runtime.h>

// GCN 3-layer, N=100000, E=1600000, D=128.
// Per launch:
//   CSR build: hist(deg by dst) -> exclusive scan(off) -> bucket(ssrc sorted by dst)
//   dinv[i] = (deg[i]+1)^-1/2
// Per layer L:
//   gemm_g: bufA = g = dinv[i] * (f(in) @ W)    (f = relu(dinv*v+b) for L>1, identity for L=1)
//   gather: bufB[i] = g[i] + sum_{e: dst=i} g[src]   (register accum, no float atomics)
// Final: out[c] = mean_i relu(dinv[i]*bufB[i][c] + b3[c])

__global__ __launch_bounds__(256) void hist_k(const int* __restrict__ ei,
                                              int* __restrict__ deg, int e) {
  int t = blockIdx.x * 256 + threadIdx.x;
  if (t < e) atomicAdd(&deg[ei[e + t]], 1);  // dst at ei[E..2E)
}

// block scans 1024 elements (256 thr x 4), writes per-block sums
__global__ __launch_bounds__(256) void scan1_k(const int* __restrict__ deg,
                                               int* __restrict__ off,
                                               int* __restrict__ bsums, int n) {
  __shared__ int s[256];
  int b = blockIdx.x, t = threadIdx.x;
  int base = b * 1024 + t * 4;
  int v0 = 0, v1 = 0, v2 = 0, v3 = 0;
  if (base + 0 < n) v0 = deg[base + 0];
  if (base + 1 < n) v1 = deg[base + 1];
  if (base + 2 < n) v2 = deg[base + 2];
  if (base + 3 < n) v3 = deg[base + 3];
  int tsum = v0 + v1 + v2 + v3;
  s[t] = tsum;
  __syncthreads();
  for (int d = 1; d < 256; d <<= 1) {
    int x = (t >= d) ? s[t - d] : 0;
    __syncthreads();
    s[t] += x;
    __syncthreads();
  }
  int excl = s[t] - tsum;
  if (t == 255) bsums[b] = s[255];
  int o0 = excl, o1 = o0 + v0, o2 = o1 + v1, o3 = o2 + v2;
  if (base + 0 < n) off[base + 0] = o0;
  if (base + 1 < n) off[base + 1] = o1;
  if (base + 2 < n) off[base + 2] = o2;
  if (base + 3 < n) off[base + 3] = o3;
}

__global__ void scan2_k(int* bsums, int nb) {
  if (threadIdx.x == 0 && blockIdx.x == 0) {
    int run = 0;
    for (int i = 0; i < nb; ++i) { int v = bsums[i]; bsums[i] = run; run += v; }
  }
}

__global__ __launch_bounds__(256) void scan3_k(int* __restrict__ off,
                                               const int* __restrict__ bsums,
                                               int n, int e) {
  int i = blockIdx.x * 256 + threadIdx.x;
  if (i < n) off[i] += bsums[i >> 10];
  if (i == 0) off[n] = e;
}

__global__ __launch_bounds__(256) void bucket_k(const int* __restrict__ ei,
                                                const int* __restrict__ off,
                                                int* __restrict__ cursor,
                                                int* __restrict__ ssrc, int e) {
  int t = blockIdx.x * 256 + threadIdx.x;
  if (t < e) {
    int d = ei[e + t];
    int p = atomicAdd(&cursor[d], 1);
    ssrc[off[d] + p] = ei[t];
  }
}

__global__ __launch_bounds__(256) void dinv_k(const int* __restrict__ deg,
                                              float* __restrict__ dinv, int n) {
  int t = blockIdx.x * 256 + threadIdx.x;
  if (t < n) dinv[t] = 1.0f / sqrtf((float)deg[t] + 1.0f);
}

// 64 rows x 128 cols per block, 256 threads, thread tile 4x8.
template <int EPI>
__global__ __launch_bounds__(256) void gemm_g(
    const float* in, const float* __restrict__ W,
    const float* __restrict__ dinv, const float* __restrict__ bias,
    float* __restrict__ outA, int n)
{
  __shared__ float s_in[64 * 33 * 4];   // 64 rows x 132 floats (pad -> free 2-way)
  __shared__ float s_w[64 * 128];       // one K-half of W
  float4* s_in4 = (float4*)s_in;
  float4* s_w4  = (float4*)s_w;
  const int t = threadIdx.x;
  const int row0 = blockIdx.x * 64;

  const float4* in4 = (const float4*)in;
  #pragma unroll
  for (int j = 0; j < 8; ++j) {
    int f = t + j * 256;
    int r = f >> 5, c4 = f & 31;
    int row = row0 + r;
    float4 v = make_float4(0.f, 0.f, 0.f, 0.f);
    if (row < n) {
      v = in4[(size_t)row * 32 + c4];
      if (EPI) {
        float dv = dinv[row];
        float4 bb = ((const float4*)bias)[c4];
        v.x = fmaxf(fmaf(dv, v.x, bb.x), 0.f);
        v.y = fmaxf(fmaf(dv, v.y, bb.y), 0.f);
        v.z = fmaxf(fmaf(dv, v.z, bb.z), 0.f);
        v.w = fmaxf(fmaf(dv, v.w, bb.w), 0.f);
      }
    }
    s_in4[r * 33 + c4] = v;
  }

  float acc[4][8];
  #pragma unroll
  for (int i = 0; i < 4; ++i)
    #pragma unroll
    for (int j = 0; j < 8; ++j) acc[i][j] = 0.f;

  const int rg = t >> 4;
  const int cg = t & 15;

  const float4* W4 = (const float4*)W;
  #pragma unroll
  for (int half = 0; half < 2; ++half) {
    __syncthreads();
    #pragma unroll
    for (int j = 0; j < 8; ++j) {
      int f = t + j * 256;
      s_w4[f] = W4[half * 2048 + f];
    }
    __syncthreads();
    for (int k4 = 0; k4 < 16; ++k4) {
      float a[4][4];
      #pragma unroll
      for (int i = 0; i < 4; ++i)
        *(float4*)a[i] = s_in4[(rg * 4 + i) * 33 + half * 16 + k4];
      #pragma unroll
      for (int kk = 0; kk < 4; ++kk) {
        float4 w0 = s_w4[(k4 * 4 + kk) * 32 + cg * 2];
        float4 w1 = s_w4[(k4 * 4 + kk) * 32 + cg * 2 + 1];
        #pragma unroll
        for (int i = 0; i < 4; ++i) {
          float av = a[i][kk];
          acc[i][0] = fmaf(av, w0.x, acc[i][0]);
          acc[i][1] = fmaf(av, w0.y, acc[i][1]);
          acc[i][2] = fmaf(av, w0.z, acc[i][2]);
          acc[i][3] = fmaf(av, w0.w, acc[i][3]);
          acc[i][4] = fmaf(av, w1.x, acc[i][4]);
          acc[i][5] = fmaf(av, w1.y, acc[i][5]);
          acc[i][6] = fmaf(av, w1.z, acc[i][6]);
          acc[i][7] = fmaf(av, w1.w, acc[i][7]);
        }
      }
    }
  }

  #pragma unroll
  for (int i = 0; i < 4; ++i) {
    int row = row0 + rg * 4 + i;
    if (row < n) {
      float dv = dinv[row];
      float4 o0, o1;
      o0.x = acc[i][0] * dv; o0.y = acc[i][1] * dv;
      o0.z = acc[i][2] * dv; o0.w = acc[i][3] * dv;
      o1.x = acc[i][4] * dv; o1.y = acc[i][5] * dv;
      o1.z = acc[i][6] * dv; o1.w = acc[i][7] * dv;
      size_t base = (size_t)row * 32 + cg * 2;
      ((float4*)outA)[base]     = o0;
      ((float4*)outA)[base + 1] = o1;
    }
  }
}

// One 64-lane wave per dst node; lane owns 2 cols (float2). Register accumulate.
__global__ __launch_bounds__(256) void gather_k(const float* __restrict__ A,
                                                float* __restrict__ B,
                                                const int* __restrict__ ssrc,
                                                const int* __restrict__ off, int n) {
  int w = (blockIdx.x * 256 + threadIdx.x) >> 6;
  int lane = threadIdx.x & 63;
  if (w >= n) return;
  const float2* A2 = (const float2*)A;
  int beg = off[w], end = off[w + 1];
  float2 acc = A2[(size_t)w * 64 + lane];   // self-loop term g[i]
  int j = beg;
  for (; j + 4 <= end; j += 4) {
    int s0 = ssrc[j], s1 = ssrc[j + 1], s2 = ssrc[j + 2], s3 = ssrc[j + 3];
    float2 v0 = A2[(size_t)s0 * 64 + lane];
    float2 v1 = A2[(size_t)s1 * 64 + lane];
    float2 v2 = A2[(size_t)s2 * 64 + lane];
    float2 v3 = A2[(size_t)s3 * 64 + lane];
    acc.x += (v0.x + v1.x) + (v2.x + v3.x);
    acc.y += (v0.y + v1.y) + (v2.y + v3.y);
  }
  for (; j < end; ++j) {
    int s = ssrc[j];
    float2 v = A2[(size_t)s * 64 + lane];
    acc.x += v.x; acc.y += v.y;
  }
  ((float2*)B)[(size_t)w * 64 + lane] = acc;
}

__global__ __launch_bounds__(128) void mean_k(const float* __restrict__ B,
                                              const float* __restrict__ dinv,
                                              const float* __restrict__ bias,
                                              float* __restrict__ out, int n, float invn) {
  int c = threadIdx.x;
  float bb = bias[c];
  float sum = 0.f;
  for (int row = blockIdx.x; row < n; row += gridDim.x) {
    float v = fmaf(dinv[row], B[(size_t)row * 128 + c], bb);
    sum += fmaxf(v, 0.f);
  }
  unsafeAtomicAdd(&out[c], sum * invn);
}

extern "C" void kernel_launch(void* const* d_in, const int* in_sizes, int n_in,
                              void* d_out, int out_size, void* d_ws, size_t ws_size,
                              hipStream_t stream) {
  const float* x  = (const float*)d_in[0];
  const int*   ei = (const int*)d_in[1];
  const float* W1 = (const float*)d_in[2];
  const float* b1 = (const float*)d_in[3];
  const float* W2 = (const float*)d_in[4];
  const float* b2 = (const float*)d_in[5];
  const float* W3 = (const float*)d_in[6];
  const float* b3 = (const float*)d_in[7];
  float* out = (float*)d_out;

  const int n = in_sizes[0] / 128;
  const int e = in_sizes[1] / 2;
  const int nb = (n + 1023) / 1024;

  // ---- workspace layout (byte offsets, 256B-aligned blocks) ----
  char* p = (char*)d_ws;
  auto alloc = [&](size_t bytes) {
    char* r = p;
    p += (bytes + 255) & ~(size_t)255;
    return r;
  };
  int*   off    = (int*)alloc((size_t)(n + 1) * 4);
  int*   deg    = (int*)alloc((size_t)n * 4);        // reused as cursor after dinv
  int*   bsums  = (int*)alloc((size_t)(nb + 1) * 4);
  float* dinv   = (float*)alloc((size_t)n * 4);
  int*   ssrc   = (int*)alloc((size_t)e * 4);
  float* bufA   = (float*)alloc((size_t)n * 128 * 4);
  float* bufB   = (float*)alloc((size_t)n * 128 * 4);

  // ---- CSR build ----
  hipMemsetAsync(deg, 0, (size_t)n * 4, stream);
  hist_k <<<(e + 255) / 256, 256, 0, stream>>>(ei, deg, e);
  scan1_k<<<nb, 256, 0, stream>>>(deg, off, bsums, n);
  scan2_k<<<1, 64, 0, stream>>>(bsums, nb);
  scan3_k<<<(n + 255) / 256, 256, 0, stream>>>(off, bsums, n, e);
  dinv_k <<<(n + 255) / 256, 256, 0, stream>>>(deg, dinv, n);
  hipMemsetAsync(deg, 0, (size_t)n * 4, stream);     // deg -> cursor
  bucket_k<<<(e + 255) / 256, 256, 0, stream>>>(ei, off, deg, ssrc, e);

  // ---- 3 GCN layers ----
  const int gb = (n + 63) / 64;
  const int ab = (n * 64 + 255) / 256;   // 1 wave per node

  gemm_g<0><<<gb, 256, 0, stream>>>(x,    W1, dinv, nullptr, bufA, n);
  gather_k <<<ab, 256, 0, stream>>>(bufA, bufB, ssrc, off, n);
  gemm_g<1><<<gb, 256, 0, stream>>>(bufB, W2, dinv, b1, bufA, n);
  gather_k <<<ab, 256, 0, stream>>>(bufA, bufB, ssrc, off, n);
  gemm_g<1><<<gb, 256, 0, stream>>>(bufB, W3, dinv, b2, bufA, n);
  gather_k <<<ab, 256, 0, stream>>>(bufA, bufB, ssrc, off, n);

  hipMemsetAsync(out, 0, 128 * sizeof(float), stream);
  mean_k<<<2048, 128, 0, stream>>>(bufB, dinv, b3, out, n, 1.0f / (float)n);
}

// Round 6
// 638.070 us; speedup vs baseline: 13.2682x; 1.3523x over previous
//
#include <hip/hip_runtime.h>

// GCN 3-layer, N=100000, E=1600000, D=128. bf16 intermediates, MFMA GEMM.
// Per launch:
//   CSR build: hist(deg by dst) -> scan(off) -> bucket(ssrc sorted by dst); dinv=(deg+1)^-1/2
//   Wt = bf16(W^T) for the 3 weights
// Per layer L:
//   gemm_g: bufA = bf16( dinv[i] * (f(in) @ W) )  (f = relu(dinv*v+b) fused into A-frag load; identity L=1)
//   gather: bufB[i] = bf16( g[i] + sum_{e: dst=i} g[src] )   (f32 accum, no float atomics)
// Final: out[c] = mean_i relu(dinv[i]*bufB[i][c] + b3[c])   (partials + tiny reduce)

typedef short bf16x8 __attribute__((ext_vector_type(8)));
typedef float f32x4 __attribute__((ext_vector_type(4)));

__device__ __forceinline__ ushort f2bf(float f) {
  uint u = __builtin_bit_cast(uint, f);
  return (ushort)((u + 0x7fffu + ((u >> 16) & 1u)) >> 16);
}
__device__ __forceinline__ float bflo(uint u) { return __builtin_bit_cast(float, u << 16); }
__device__ __forceinline__ float bfhi(uint u) { return __builtin_bit_cast(float, u & 0xffff0000u); }
__device__ __forceinline__ uint packbf(float x, float y) {
  uint ux = __builtin_bit_cast(uint, x), uy = __builtin_bit_cast(uint, y);
  uint rx = (ux + 0x7fffu + ((ux >> 16) & 1u)) >> 16;
  uint ry = (uy + 0x7fffu + ((uy >> 16) & 1u)) & 0xffff0000u;
  return rx | ry;
}

// ---------------- CSR build ----------------
__global__ __launch_bounds__(256) void hist_k(const int* __restrict__ ei,
                                              int* __restrict__ deg, int e) {
  int t = blockIdx.x * 256 + threadIdx.x;
  if (t < e) atomicAdd(&deg[ei[e + t]], 1);  // dst at ei[E..2E)
}

__global__ __launch_bounds__(256) void scan1_k(const int* __restrict__ deg,
                                               int* __restrict__ off,
                                               int* __restrict__ bsums, int n) {
  __shared__ int s[256];
  int b = blockIdx.x, t = threadIdx.x;
  int base = b * 1024 + t * 4;
  int v0 = 0, v1 = 0, v2 = 0, v3 = 0;
  if (base + 0 < n) v0 = deg[base + 0];
  if (base + 1 < n) v1 = deg[base + 1];
  if (base + 2 < n) v2 = deg[base + 2];
  if (base + 3 < n) v3 = deg[base + 3];
  int tsum = v0 + v1 + v2 + v3;
  s[t] = tsum;
  __syncthreads();
  for (int d = 1; d < 256; d <<= 1) {
    int x = (t >= d) ? s[t - d] : 0;
    __syncthreads();
    s[t] += x;
    __syncthreads();
  }
  int excl = s[t] - tsum;
  if (t == 255) bsums[b] = s[255];
  int o0 = excl, o1 = o0 + v0, o2 = o1 + v1, o3 = o2 + v2;
  if (base + 0 < n) off[base + 0] = o0;
  if (base + 1 < n) off[base + 1] = o1;
  if (base + 2 < n) off[base + 2] = o2;
  if (base + 3 < n) off[base + 3] = o3;
}

__global__ __launch_bounds__(1024) void scan2_k(int* __restrict__ bsums, int nb) {
  __shared__ int s[1024];
  int t = threadIdx.x;
  int v = (t < nb) ? bsums[t] : 0;
  s[t] = v;
  __syncthreads();
  for (int d = 1; d < 1024; d <<= 1) {
    int x = (t >= d) ? s[t - d] : 0;
    __syncthreads();
    s[t] += x;
    __syncthreads();
  }
  if (t < nb) bsums[t] = s[t] - v;
}

__global__ __launch_bounds__(256) void scan3_k(int* __restrict__ off,
                                               const int* __restrict__ bsums,
                                               int n, int e) {
  int i = blockIdx.x * 256 + threadIdx.x;
  if (i < n) off[i] += bsums[i >> 10];
  if (i == 0) off[n] = e;
}

__global__ __launch_bounds__(256) void bucket_k(const int* __restrict__ ei,
                                                const int* __restrict__ off,
                                                int* __restrict__ cursor,
                                                int* __restrict__ ssrc, int e) {
  int t = blockIdx.x * 256 + threadIdx.x;
  if (t < e) {
    int d = ei[e + t];
    int p = atomicAdd(&cursor[d], 1);
    ssrc[off[d] + p] = ei[t];
  }
}

__global__ __launch_bounds__(256) void dinv_k(const int* __restrict__ deg,
                                              float* __restrict__ dinv, int n) {
  int t = blockIdx.x * 256 + threadIdx.x;
  if (t < n) dinv[t] = 1.0f / sqrtf((float)deg[t] + 1.0f);
}

// ---------------- W^T cast (3 matrices, 128x128 each) ----------------
__global__ __launch_bounds__(256) void wtcast_k(const float* __restrict__ W1,
                                                const float* __restrict__ W2,
                                                const float* __restrict__ W3,
                                                ushort* __restrict__ Wt1,
                                                ushort* __restrict__ Wt2,
                                                ushort* __restrict__ Wt3) {
  int b = blockIdx.x;
  const float* W = (b < 64) ? W1 : ((b < 128) ? W2 : W3);
  ushort* Wt = (b < 64) ? Wt1 : ((b < 128) ? Wt2 : Wt3);
  int idx = (b & 63) * 256 + threadIdx.x;   // 0..16383 ; idx = n*128 + k
  int nn = idx >> 7, kk = idx & 127;
  Wt[idx] = f2bf(W[kk * 128 + nn]);
}

// ---------------- MFMA GEMM: 1 wave = 16 rows x 128 cols, no LDS ----------------
// A-frag (16x16x32 bf16): lane l holds A[row = l&15][k = (l>>4)*8 + j], j=0..7
// B-frag:                 lane l holds B[k = (l>>4)*8 + j][col = l&15]  (from Wt[col][k])
// C/D:                    lane l, reg j -> (row = (l>>4)*4 + j, col = l&15)   [m89]
template <int EPI>
__global__ __launch_bounds__(256) void gemm_g(
    const void* __restrict__ inv_, const ushort* __restrict__ Wt,
    const float* __restrict__ dinv, const float* __restrict__ bias,
    ushort* __restrict__ outA, int n)
{
  const int t = threadIdx.x;
  const int wid = t >> 6, lane = t & 63;
  const int rbase = blockIdx.x * 64 + wid * 16;
  if (rbase >= n) return;

  const int l16 = lane & 15, kc = lane >> 4, k0 = kc * 8;
  int arow = rbase + l16;
  bool rok = arow < n;
  int arow_c = rok ? arow : (n - 1);

  bf16x8 afr[4];
  if constexpr (EPI) {
    const ushort* in = (const ushort*)inv_;
    float dv = dinv[arow_c];
    #pragma unroll
    for (int kk = 0; kk < 4; ++kk) {
      uint4 r4 = *(const uint4*)(in + (size_t)arow_c * 128 + kk * 32 + k0);
      float4 bb0 = *(const float4*)(bias + kk * 32 + k0);
      float4 bb1 = *(const float4*)(bias + kk * 32 + k0 + 4);
      uint rr[4] = {r4.x, r4.y, r4.z, r4.w};
      float bb[8] = {bb0.x, bb0.y, bb0.z, bb0.w, bb1.x, bb1.y, bb1.z, bb1.w};
      bf16x8 a;
      #pragma unroll
      for (int q = 0; q < 4; ++q) {
        float lo = fmaxf(fmaf(dv, bflo(rr[q]), bb[2 * q]), 0.f);
        float hi = fmaxf(fmaf(dv, bfhi(rr[q]), bb[2 * q + 1]), 0.f);
        a[2 * q]     = (short)f2bf(lo);
        a[2 * q + 1] = (short)f2bf(hi);
      }
      afr[kk] = rok ? a : (bf16x8)0;
    }
  } else {
    const float4* in4 = (const float4*)inv_;
    #pragma unroll
    for (int kk = 0; kk < 4; ++kk) {
      float4 p0 = in4[(size_t)arow_c * 32 + kk * 8 + kc * 2];
      float4 p1 = in4[(size_t)arow_c * 32 + kk * 8 + kc * 2 + 1];
      float f[8] = {p0.x, p0.y, p0.z, p0.w, p1.x, p1.y, p1.z, p1.w};
      bf16x8 a;
      #pragma unroll
      for (int q = 0; q < 8; ++q) a[q] = (short)f2bf(f[q]);
      afr[kk] = rok ? a : (bf16x8)0;
    }
  }

  f32x4 acc[8];
  #pragma unroll
  for (int nt = 0; nt < 8; ++nt) acc[nt] = (f32x4){0.f, 0.f, 0.f, 0.f};

  #pragma unroll
  for (int kk = 0; kk < 4; ++kk) {
    #pragma unroll
    for (int nt = 0; nt < 8; ++nt) {
      bf16x8 bfr = *(const bf16x8*)(Wt + (size_t)(nt * 16 + l16) * 128 + kk * 32 + k0);
      acc[nt] = __builtin_amdgcn_mfma_f32_16x16x32_bf16(afr[kk], bfr, acc[nt], 0, 0, 0);
    }
  }

  // epilogue: g = dinv[row] * acc -> bf16 store
  float dvr[4];
  int rr[4];
  #pragma unroll
  for (int j = 0; j < 4; ++j) {
    rr[j] = rbase + kc * 4 + j;
    dvr[j] = (rr[j] < n) ? dinv[rr[j]] : 0.f;
  }
  #pragma unroll
  for (int nt = 0; nt < 8; ++nt) {
    int col = nt * 16 + l16;
    #pragma unroll
    for (int j = 0; j < 4; ++j) {
      if (rr[j] < n)
        outA[(size_t)rr[j] * 128 + col] = f2bf(acc[nt][j] * dvr[j]);
    }
  }
}

// ---------------- gather: 1 wave per dst node, bf16 rows, f32 accum ----------------
__global__ __launch_bounds__(256) void gather_k(const uint* __restrict__ A,
                                                uint* __restrict__ B,
                                                const int* __restrict__ ssrc,
                                                const int* __restrict__ off, int n) {
  int w = (blockIdx.x * 256 + threadIdx.x) >> 6;
  int lane = threadIdx.x & 63;
  if (w >= n) return;
  int beg = off[w], end = off[w + 1];
  uint sv = A[(size_t)w * 64 + lane];        // self-loop term g[i]
  float ax = bflo(sv), ay = bfhi(sv);
  int j = beg;
  for (; j + 4 <= end; j += 4) {
    int s0 = ssrc[j], s1 = ssrc[j + 1], s2 = ssrc[j + 2], s3 = ssrc[j + 3];
    uint v0 = A[(size_t)s0 * 64 + lane];
    uint v1 = A[(size_t)s1 * 64 + lane];
    uint v2 = A[(size_t)s2 * 64 + lane];
    uint v3 = A[(size_t)s3 * 64 + lane];
    ax += (bflo(v0) + bflo(v1)) + (bflo(v2) + bflo(v3));
    ay += (bfhi(v0) + bfhi(v1)) + (bfhi(v2) + bfhi(v3));
  }
  for (; j < end; ++j) {
    uint v = A[(size_t)ssrc[j] * 64 + lane];
    ax += bflo(v); ay += bfhi(v);
  }
  B[(size_t)w * 64 + lane] = packbf(ax, ay);
}

// ---------------- mean: partials then reduce ----------------
__global__ __launch_bounds__(256) void mean1_k(const uint* __restrict__ B,
                                               const float* __restrict__ dinv,
                                               const float* __restrict__ bias,
                                               float* __restrict__ part, int n) {
  __shared__ float s[512];
  int t = threadIdx.x, cg = t & 63, rg = t >> 6;
  float bx = bias[cg * 2], by = bias[cg * 2 + 1];
  float sx = 0.f, sy = 0.f;
  for (int row = blockIdx.x * 4 + rg; row < n; row += 1024) {
    uint v = B[(size_t)row * 64 + cg];
    float dv = dinv[row];
    sx += fmaxf(fmaf(dv, bflo(v), bx), 0.f);
    sy += fmaxf(fmaf(dv, bfhi(v), by), 0.f);
  }
  s[t * 2] = sx; s[t * 2 + 1] = sy;
  __syncthreads();
  if (t < 64) {
    float rx = s[t * 2] + s[(t + 64) * 2] + s[(t + 128) * 2] + s[(t + 192) * 2];
    float ry = s[t * 2 + 1] + s[(t + 64) * 2 + 1] + s[(t + 128) * 2 + 1] + s[(t + 192) * 2 + 1];
    part[blockIdx.x * 128 + cg * 2] = rx;
    part[blockIdx.x * 128 + cg * 2 + 1] = ry;
  }
}

__global__ __launch_bounds__(128) void mean2_k(const float* __restrict__ part,
                                               float* __restrict__ out, float invn) {
  int c = threadIdx.x;
  float s = 0.f;
  for (int b = 0; b < 256; ++b) s += part[b * 128 + c];
  out[c] = s * invn;
}

extern "C" void kernel_launch(void* const* d_in, const int* in_sizes, int n_in,
                              void* d_out, int out_size, void* d_ws, size_t ws_size,
                              hipStream_t stream) {
  const float* x  = (const float*)d_in[0];
  const int*   ei = (const int*)d_in[1];
  const float* W1 = (const float*)d_in[2];
  const float* b1 = (const float*)d_in[3];
  const float* W2 = (const float*)d_in[4];
  const float* b2 = (const float*)d_in[5];
  const float* W3 = (const float*)d_in[6];
  const float* b3 = (const float*)d_in[7];
  float* out = (float*)d_out;

  const int n = in_sizes[0] / 128;
  const int e = in_sizes[1] / 2;
  const int nb = (n + 1023) / 1024;

  char* p = (char*)d_ws;
  auto alloc = [&](size_t bytes) {
    char* r = p;
    p += (bytes + 255) & ~(size_t)255;
    return r;
  };
  int*    off   = (int*)alloc((size_t)(n + 1) * 4);
  int*    deg   = (int*)alloc((size_t)n * 4);        // reused as cursor
  int*    bsums = (int*)alloc(1024 * 4);
  float*  dinv  = (float*)alloc((size_t)n * 4);
  int*    ssrc  = (int*)alloc((size_t)e * 4);
  ushort* Wt1   = (ushort*)alloc(128 * 128 * 2);
  ushort* Wt2   = (ushort*)alloc(128 * 128 * 2);
  ushort* Wt3   = (ushort*)alloc(128 * 128 * 2);
  ushort* bufA  = (ushort*)alloc((size_t)n * 128 * 2);
  ushort* bufB  = (ushort*)alloc((size_t)n * 128 * 2);
  float*  part  = (float*)alloc(256 * 128 * 4);

  // CSR build + dinv + Wt
  hipMemsetAsync(deg, 0, (size_t)n * 4, stream);
  hist_k <<<(e + 255) / 256, 256, 0, stream>>>(ei, deg, e);
  scan1_k<<<nb, 256, 0, stream>>>(deg, off, bsums, n);
  scan2_k<<<1, 1024, 0, stream>>>(bsums, nb);
  scan3_k<<<(n + 255) / 256, 256, 0, stream>>>(off, bsums, n, e);
  dinv_k <<<(n + 255) / 256, 256, 0, stream>>>(deg, dinv, n);
  hipMemsetAsync(deg, 0, (size_t)n * 4, stream);     // deg -> cursor
  bucket_k<<<(e + 255) / 256, 256, 0, stream>>>(ei, off, deg, ssrc, e);
  wtcast_k<<<192, 256, 0, stream>>>(W1, W2, W3, Wt1, Wt2, Wt3);

  const int gb = (n + 63) / 64;
  const int ab = (n * 64 + 255) / 256;

  gemm_g<0><<<gb, 256, 0, stream>>>(x, Wt1, dinv, nullptr, bufA, n);
  gather_k <<<ab, 256, 0, stream>>>((const uint*)bufA, (uint*)bufB, ssrc, off, n);
  gemm_g<1><<<gb, 256, 0, stream>>>(bufB, Wt2, dinv, b1, bufA, n);
  gather_k <<<ab, 256, 0, stream>>>((const uint*)bufA, (uint*)bufB, ssrc, off, n);
  gemm_g<1><<<gb, 256, 0, stream>>>(bufB, Wt3, dinv, b2, bufA, n);
  gather_k <<<ab, 256, 0, stream>>>((const uint*)bufA, (uint*)bufB, ssrc, off, n);

  mean1_k<<<256, 256, 0, stream>>>((const uint*)bufB, dinv, b3, part, n);
  mean2_k<<<1, 128, 0, stream>>>(part, out, 1.0f / (float)n);
}

// Round 7
// 522.936 us; speedup vs baseline: 16.1895x; 1.2202x over previous
//
#include <hip/hip_runtime.h>

// GCN 3-layer, N=100000, E=1600000, D=128. bf16 intermediates, MFMA GEMM.
// CSR build (tile-binned, LDS-staged; 256-node tiles, NB=ceil(n/256) bins):
//   chist_k:      LDS hist of dst>>8 per 8192-edge chunk -> global cnt[NB]
//   cscan_k:      1-block scan -> cbase[] (exclusive), ccur[] copy, off[n]=e
//   binscatter_k: per-chunk LDS hist -> bulk range reserve -> write bpak = src|dstLocal<<24
//   binsort_k:    1 block/tile: counting sort by dstLocal -> ssrc; emits off[] and dinv[]
// Per layer L:
//   gemm_g:  bufA = bf16( dinv[i] * (f(in) @ W) )   (f = relu(dinv*v+b) fused; identity L=1)
//   gather:  bufB[i] = bf16( g[i] + sum_{e: dst=i} g[src] )   (f32 accum, no float atomics)
// Final: out[c] = mean_i relu(dinv[i]*bufB[i][c] + b3[c])

typedef short bf16x8 __attribute__((ext_vector_type(8)));
typedef float f32x4 __attribute__((ext_vector_type(4)));

__device__ __forceinline__ ushort f2bf(float f) {
  uint u = __builtin_bit_cast(uint, f);
  return (ushort)((u + 0x7fffu + ((u >> 16) & 1u)) >> 16);
}
__device__ __forceinline__ float bflo(uint u) { return __builtin_bit_cast(float, u << 16); }
__device__ __forceinline__ float bfhi(uint u) { return __builtin_bit_cast(float, u & 0xffff0000u); }
__device__ __forceinline__ uint packbf(float x, float y) {
  uint ux = __builtin_bit_cast(uint, x), uy = __builtin_bit_cast(uint, y);
  uint rx = (ux + 0x7fffu + ((ux >> 16) & 1u)) >> 16;
  uint ry = (uy + 0x7fffu + ((uy >> 16) & 1u)) & 0xffff0000u;
  return rx | ry;
}

#define CHUNK 8192

// ---------------- CSR build (tile-binned) ----------------
__global__ __launch_bounds__(256) void chist_k(const int* __restrict__ ei,
                                               int* __restrict__ cnt, int e, int nb) {
  __shared__ int h[512];
  int t = threadIdx.x;
  for (int i = t; i < nb; i += 256) h[i] = 0;
  __syncthreads();
  int base = blockIdx.x * CHUNK;
  int lim = min(base + CHUNK, e);
  for (int i = base + t; i < lim; i += 256)
    atomicAdd(&h[ei[e + i] >> 8], 1);           // dst at ei[E..2E)
  __syncthreads();
  for (int i = t; i < nb; i += 256) if (h[i]) atomicAdd(&cnt[i], h[i]);
}

// nb <= 512 (n <= 131072). Exclusive scan + cursor copy + off[n]=e.
__global__ __launch_bounds__(512) void cscan_k(const int* __restrict__ cnt,
                                               int* __restrict__ cbase,
                                               int* __restrict__ ccur,
                                               int* __restrict__ off,
                                               int nb, int n, int e) {
  __shared__ int s[512];
  int t = threadIdx.x;
  int v = (t < nb) ? cnt[t] : 0;
  s[t] = v;
  __syncthreads();
  for (int d = 1; d < 512; d <<= 1) {
    int x = (t >= d) ? s[t - d] : 0;
    __syncthreads();
    s[t] += x;
    __syncthreads();
  }
  int excl = s[t] - v;
  if (t < nb) { cbase[t] = excl; ccur[t] = excl; }
  if (t == 0) { cbase[nb] = e; off[n] = e; }
}

__global__ __launch_bounds__(256) void binscatter_k(const int* __restrict__ ei,
                                                    int* __restrict__ ccur,
                                                    uint* __restrict__ bpak,
                                                    int e, int nb) {
  __shared__ int lhist[512], gbase[512], lcur[512];
  int t = threadIdx.x;
  for (int i = t; i < nb; i += 256) lhist[i] = 0;
  __syncthreads();
  int base = blockIdx.x * CHUNK;
  int lim = min(base + CHUNK, e);
  for (int i = base + t; i < lim; i += 256)
    atomicAdd(&lhist[ei[e + i] >> 8], 1);
  __syncthreads();
  for (int i = t; i < nb; i += 256) {
    int c = lhist[i];
    gbase[i] = c ? atomicAdd(&ccur[i], c) : 0;
    lcur[i] = 0;
  }
  __syncthreads();
  for (int i = base + t; i < lim; i += 256) {
    int d = ei[e + i];
    int s = ei[i];
    int bin = d >> 8;
    int slot = atomicAdd(&lcur[bin], 1);
    bpak[gbase[bin] + slot] = (uint)s | ((uint)(d & 255) << 24);
  }
}

// One block per 256-node tile: counting sort by dstLocal; emits ssrc, off, dinv.
__global__ __launch_bounds__(256) void binsort_k(const uint* __restrict__ bpak,
                                                 const int* __restrict__ cbase,
                                                 float* __restrict__ dinv,
                                                 int* __restrict__ off,
                                                 int* __restrict__ ssrc, int n) {
  __shared__ int hist[256], cur[256], sc[256];
  int b = blockIdx.x, t = threadIdx.x;
  int beg = cbase[b], end = cbase[b + 1];
  hist[t] = 0;
  __syncthreads();
  for (int j = beg + t; j < end; j += 256) atomicAdd(&hist[bpak[j] >> 24], 1);
  __syncthreads();
  int cnt = hist[t];
  sc[t] = cnt;
  __syncthreads();
  for (int d = 1; d < 256; d <<= 1) {
    int x = (t >= d) ? sc[t - d] : 0;
    __syncthreads();
    sc[t] += x;
    __syncthreads();
  }
  int excl = sc[t] - cnt;
  cur[t] = excl;
  int node = b * 256 + t;
  if (node < n) {
    dinv[node] = rsqrtf((float)cnt + 1.0f);
    off[node] = beg + excl;
  }
  __syncthreads();
  for (int j = beg + t; j < end; j += 256) {
    uint pak = bpak[j];
    int pos = atomicAdd(&cur[pak >> 24], 1);
    ssrc[beg + pos] = (int)(pak & 0xFFFFFFu);
  }
}

// ---------------- W^T cast (3 matrices, 128x128 each) ----------------
__global__ __launch_bounds__(256) void wtcast_k(const float* __restrict__ W1,
                                                const float* __restrict__ W2,
                                                const float* __restrict__ W3,
                                                ushort* __restrict__ Wt1,
                                                ushort* __restrict__ Wt2,
                                                ushort* __restrict__ Wt3) {
  int b = blockIdx.x;
  const float* W = (b < 64) ? W1 : ((b < 128) ? W2 : W3);
  ushort* Wt = (b < 64) ? Wt1 : ((b < 128) ? Wt2 : Wt3);
  int idx = (b & 63) * 256 + threadIdx.x;   // idx = n*128 + k
  int nn = idx >> 7, kk = idx & 127;
  Wt[idx] = f2bf(W[kk * 128 + nn]);
}

// ---------------- MFMA GEMM: 1 wave = 16 rows x 128 cols, no LDS ----------------
// A-frag (16x16x32 bf16): lane l holds A[row = l&15][k = (l>>4)*8 + j], j=0..7
// B-frag:                 lane l holds B[k = (l>>4)*8 + j][col = l&15]  (from Wt[col][k])
// C/D:                    lane l, reg j -> (row = (l>>4)*4 + j, col = l&15)   [m89]
template <int EPI>
__global__ __launch_bounds__(256) void gemm_g(
    const void* __restrict__ inv_, const ushort* __restrict__ Wt,
    const float* __restrict__ dinv, const float* __restrict__ bias,
    ushort* __restrict__ outA, int n)
{
  const int t = threadIdx.x;
  const int wid = t >> 6, lane = t & 63;
  const int rbase = blockIdx.x * 64 + wid * 16;
  if (rbase >= n) return;

  const int l16 = lane & 15, kc = lane >> 4, k0 = kc * 8;
  int arow = rbase + l16;
  bool rok = arow < n;
  int arow_c = rok ? arow : (n - 1);

  bf16x8 afr[4];
  if constexpr (EPI) {
    const ushort* in = (const ushort*)inv_;
    float dv = dinv[arow_c];
    #pragma unroll
    for (int kk = 0; kk < 4; ++kk) {
      uint4 r4 = *(const uint4*)(in + (size_t)arow_c * 128 + kk * 32 + k0);
      float4 bb0 = *(const float4*)(bias + kk * 32 + k0);
      float4 bb1 = *(const float4*)(bias + kk * 32 + k0 + 4);
      uint rr[4] = {r4.x, r4.y, r4.z, r4.w};
      float bb[8] = {bb0.x, bb0.y, bb0.z, bb0.w, bb1.x, bb1.y, bb1.z, bb1.w};
      bf16x8 a;
      #pragma unroll
      for (int q = 0; q < 4; ++q) {
        float lo = fmaxf(fmaf(dv, bflo(rr[q]), bb[2 * q]), 0.f);
        float hi = fmaxf(fmaf(dv, bfhi(rr[q]), bb[2 * q + 1]), 0.f);
        a[2 * q]     = (short)f2bf(lo);
        a[2 * q + 1] = (short)f2bf(hi);
      }
      afr[kk] = rok ? a : (bf16x8)0;
    }
  } else {
    const float4* in4 = (const float4*)inv_;
    #pragma unroll
    for (int kk = 0; kk < 4; ++kk) {
      float4 p0 = in4[(size_t)arow_c * 32 + kk * 8 + kc * 2];
      float4 p1 = in4[(size_t)arow_c * 32 + kk * 8 + kc * 2 + 1];
      float f[8] = {p0.x, p0.y, p0.z, p0.w, p1.x, p1.y, p1.z, p1.w};
      bf16x8 a;
      #pragma unroll
      for (int q = 0; q < 8; ++q) a[q] = (short)f2bf(f[q]);
      afr[kk] = rok ? a : (bf16x8)0;
    }
  }

  f32x4 acc[8];
  #pragma unroll
  for (int nt = 0; nt < 8; ++nt) acc[nt] = (f32x4){0.f, 0.f, 0.f, 0.f};

  #pragma unroll
  for (int kk = 0; kk < 4; ++kk) {
    #pragma unroll
    for (int nt = 0; nt < 8; ++nt) {
      bf16x8 bfr = *(const bf16x8*)(Wt + (size_t)(nt * 16 + l16) * 128 + kk * 32 + k0);
      acc[nt] = __builtin_amdgcn_mfma_f32_16x16x32_bf16(afr[kk], bfr, acc[nt], 0, 0, 0);
    }
  }

  // epilogue: g = dinv[row] * acc -> bf16 store
  float dvr[4];
  int rr[4];
  #pragma unroll
  for (int j = 0; j < 4; ++j) {
    rr[j] = rbase + kc * 4 + j;
    dvr[j] = (rr[j] < n) ? dinv[rr[j]] : 0.f;
  }
  #pragma unroll
  for (int nt = 0; nt < 8; ++nt) {
    int col = nt * 16 + l16;
    #pragma unroll
    for (int j = 0; j < 4; ++j) {
      if (rr[j] < n)
        outA[(size_t)rr[j] * 128 + col] = f2bf(acc[nt][j] * dvr[j]);
    }
  }
}

// ---------------- gather: 1 wave per dst node, bf16 rows, f32 accum ----------------
__global__ __launch_bounds__(256) void gather_k(const uint* __restrict__ A,
                                                uint* __restrict__ B,
                                                const int* __restrict__ ssrc,
                                                const int* __restrict__ off, int n) {
  int w = (blockIdx.x * 256 + threadIdx.x) >> 6;
  int lane = threadIdx.x & 63;
  if (w >= n) return;
  int beg = off[w], end = off[w + 1];
  uint sv = A[(size_t)w * 64 + lane];        // self-loop term g[i]
  float ax = bflo(sv), ay = bfhi(sv);
  int j = beg;
  for (; j + 4 <= end; j += 4) {
    int s0 = ssrc[j], s1 = ssrc[j + 1], s2 = ssrc[j + 2], s3 = ssrc[j + 3];
    uint v0 = A[(size_t)s0 * 64 + lane];
    uint v1 = A[(size_t)s1 * 64 + lane];
    uint v2 = A[(size_t)s2 * 64 + lane];
    uint v3 = A[(size_t)s3 * 64 + lane];
    ax += (bflo(v0) + bflo(v1)) + (bflo(v2) + bflo(v3));
    ay += (bfhi(v0) + bfhi(v1)) + (bfhi(v2) + bfhi(v3));
  }
  for (; j < end; ++j) {
    uint v = A[(size_t)ssrc[j] * 64 + lane];
    ax += bflo(v); ay += bfhi(v);
  }
  B[(size_t)w * 64 + lane] = packbf(ax, ay);
}

// ---------------- mean: partials then reduce ----------------
__global__ __launch_bounds__(256) void mean1_k(const uint* __restrict__ B,
                                               const float* __restrict__ dinv,
                                               const float* __restrict__ bias,
                                               float* __restrict__ part, int n) {
  __shared__ float s[512];
  int t = threadIdx.x, cg = t & 63, rg = t >> 6;
  float bx = bias[cg * 2], by = bias[cg * 2 + 1];
  float sx = 0.f, sy = 0.f;
  for (int row = blockIdx.x * 4 + rg; row < n; row += 1024) {
    uint v = B[(size_t)row * 64 + cg];
    float dv = dinv[row];
    sx += fmaxf(fmaf(dv, bflo(v), bx), 0.f);
    sy += fmaxf(fmaf(dv, bfhi(v), by), 0.f);
  }
  s[t * 2] = sx; s[t * 2 + 1] = sy;
  __syncthreads();
  if (t < 64) {
    float rx = s[t * 2] + s[(t + 64) * 2] + s[(t + 128) * 2] + s[(t + 192) * 2];
    float ry = s[t * 2 + 1] + s[(t + 64) * 2 + 1] + s[(t + 128) * 2 + 1] + s[(t + 192) * 2 + 1];
    part[blockIdx.x * 128 + cg * 2] = rx;
    part[blockIdx.x * 128 + cg * 2 + 1] = ry;
  }
}

__global__ __launch_bounds__(128) void mean2_k(const float* __restrict__ part,
                                               float* __restrict__ out, float invn) {
  int c = threadIdx.x;
  float s = 0.f;
  for (int b = 0; b < 256; ++b) s += part[b * 128 + c];
  out[c] = s * invn;
}

extern "C" void kernel_launch(void* const* d_in, const int* in_sizes, int n_in,
                              void* d_out, int out_size, void* d_ws, size_t ws_size,
                              hipStream_t stream) {
  const float* x  = (const float*)d_in[0];
  const int*   ei = (const int*)d_in[1];
  const float* W1 = (const float*)d_in[2];
  const float* b1 = (const float*)d_in[3];
  const float* W2 = (const float*)d_in[4];
  const float* b2 = (const float*)d_in[5];
  const float* W3 = (const float*)d_in[6];
  const float* b3 = (const float*)d_in[7];
  float* out = (float*)d_out;

  const int n = in_sizes[0] / 128;
  const int e = in_sizes[1] / 2;
  const int nb = (n + 255) / 256;          // 256-node tiles (nb <= 512)
  const int nchunk = (e + CHUNK - 1) / CHUNK;

  char* p = (char*)d_ws;
  auto alloc = [&](size_t bytes) {
    char* r = p;
    p += (bytes + 255) & ~(size_t)255;
    return r;
  };
  int*    cnt   = (int*)alloc((size_t)nb * 4);
  int*    cbase = (int*)alloc((size_t)(nb + 1) * 4);
  int*    ccur  = (int*)alloc((size_t)nb * 4);
  int*    off   = (int*)alloc((size_t)(n + 1) * 4);
  float*  dinv  = (float*)alloc((size_t)n * 4);
  uint*   bpak  = (uint*)alloc((size_t)e * 4);
  int*    ssrc  = (int*)alloc((size_t)e * 4);
  ushort* Wt1   = (ushort*)alloc(128 * 128 * 2);
  ushort* Wt2   = (ushort*)alloc(128 * 128 * 2);
  ushort* Wt3   = (ushort*)alloc(128 * 128 * 2);
  ushort* bufA  = (ushort*)alloc((size_t)n * 128 * 2);
  ushort* bufB  = (ushort*)alloc((size_t)n * 128 * 2);
  float*  part  = (float*)alloc(256 * 128 * 4);

  // CSR build (tile-binned) + dinv + Wt
  hipMemsetAsync(cnt, 0, (size_t)nb * 4, stream);
  chist_k     <<<nchunk, 256, 0, stream>>>(ei, cnt, e, nb);
  cscan_k     <<<1, 512, 0, stream>>>(cnt, cbase, ccur, off, nb, n, e);
  binscatter_k<<<nchunk, 256, 0, stream>>>(ei, ccur, bpak, e, nb);
  binsort_k   <<<nb, 256, 0, stream>>>(bpak, cbase, dinv, off, ssrc, n);
  wtcast_k    <<<192, 256, 0, stream>>>(W1, W2, W3, Wt1, Wt2, Wt3);

  const int gb = (n + 63) / 64;
  const int ab = (n * 64 + 255) / 256;

  gemm_g<0><<<gb, 256, 0, stream>>>(x, Wt1, dinv, nullptr, bufA, n);
  gather_k <<<ab, 256, 0, stream>>>((const uint*)bufA, (uint*)bufB, ssrc, off, n);
  gemm_g<1><<<gb, 256, 0, stream>>>(bufB, Wt2, dinv, b1, bufA, n);
  gather_k <<<ab, 256, 0, stream>>>((const uint*)bufA, (uint*)bufB, ssrc, off, n);
  gemm_g<1><<<gb, 256, 0, stream>>>(bufB, Wt3, dinv, b2, bufA, n);
  gather_k <<<ab, 256, 0, stream>>>((const uint*)bufA, (uint*)bufB, ssrc, off, n);

  mean1_k<<<256, 256, 0, stream>>>((const uint*)bufB, dinv, b3, part, n);
  mean2_k<<<1, 128, 0, stream>>>(part, out, 1.0f / (float)n);
}

// Round 11
// 433.161 us; speedup vs baseline: 19.5448x; 1.2073x over previous
//
#include <hip/hip_runtime.h>

// GCN 3-layer, N=100000, E=1600000, D=128. bf16 intermediates, MFMA GEMM.
// CSR build (tile-binned, LDS-staged; 256-node tiles, NB=ceil(n/256) bins):
//   chist_k:      LDS hist of dst>>8 per 8192-edge chunk -> global cnt[NB]
//   cscan_k:      1-block scan -> cbase[] (exclusive), ccur[] copy, off[n]=e
//   binscatter_k: per-chunk LDS hist -> bulk range reserve -> write bpak = src|dstLocal<<24
//   binsort_k:    1 block/tile: counting sort by dstLocal -> ssrc; emits off[] and dinv[]
// Per layer L:
//   gemm_g:  bufA = bf16( dinv[i] * (f(in) @ W) )   (f = relu(dinv*v+b) fused; identity L=1)
//            Wt staged in LDS (32KB, 16B-slot XOR swizzle -> 2-way banks = free)
//   gather:  bufB[i] = bf16( g[i] + sum_{e: dst=i} g[src] )   (8-deep load pipeline)
// Final: out[c] = mean_i relu(dinv[i]*bufB[i][c] + b3[c])

typedef short bf16x8 __attribute__((ext_vector_type(8)));
typedef float f32x4 __attribute__((ext_vector_type(4)));

__device__ __forceinline__ ushort f2bf(float f) {
  uint u = __builtin_bit_cast(uint, f);
  return (ushort)((u + 0x7fffu + ((u >> 16) & 1u)) >> 16);
}
__device__ __forceinline__ float bflo(uint u) { return __builtin_bit_cast(float, u << 16); }
__device__ __forceinline__ float bfhi(uint u) { return __builtin_bit_cast(float, u & 0xffff0000u); }
__device__ __forceinline__ uint packbf(float x, float y) {
  uint ux = __builtin_bit_cast(uint, x), uy = __builtin_bit_cast(uint, y);
  uint rx = (ux + 0x7fffu + ((ux >> 16) & 1u)) >> 16;
  uint ry = (uy + 0x7fffu + ((uy >> 16) & 1u)) & 0xffff0000u;
  return rx | ry;
}

#define CHUNK 8192

// ---------------- CSR build (tile-binned) ----------------
__global__ __launch_bounds__(256) void chist_k(const int* __restrict__ ei,
                                               int* __restrict__ cnt, int e, int nb) {
  __shared__ int h[512];
  int t = threadIdx.x;
  for (int i = t; i < nb; i += 256) h[i] = 0;
  __syncthreads();
  int base = blockIdx.x * CHUNK;
  int lim = min(base + CHUNK, e);
  for (int i = base + t; i < lim; i += 256)
    atomicAdd(&h[ei[e + i] >> 8], 1);           // dst at ei[E..2E)
  __syncthreads();
  for (int i = t; i < nb; i += 256) if (h[i]) atomicAdd(&cnt[i], h[i]);
}

// nb <= 512 (n <= 131072). Exclusive scan + cursor copy + off[n]=e.
__global__ __launch_bounds__(512) void cscan_k(const int* __restrict__ cnt,
                                               int* __restrict__ cbase,
                                               int* __restrict__ ccur,
                                               int* __restrict__ off,
                                               int nb, int n, int e) {
  __shared__ int s[512];
  int t = threadIdx.x;
  int v = (t < nb) ? cnt[t] : 0;
  s[t] = v;
  __syncthreads();
  for (int d = 1; d < 512; d <<= 1) {
    int x = (t >= d) ? s[t - d] : 0;
    __syncthreads();
    s[t] += x;
    __syncthreads();
  }
  int excl = s[t] - v;
  if (t < nb) { cbase[t] = excl; ccur[t] = excl; }
  if (t == 0) { cbase[nb] = e; off[n] = e; }
}

__global__ __launch_bounds__(256) void binscatter_k(const int* __restrict__ ei,
                                                    int* __restrict__ ccur,
                                                    uint* __restrict__ bpak,
                                                    int e, int nb) {
  __shared__ int lhist[512], gbase[512], lcur[512];
  int t = threadIdx.x;
  for (int i = t; i < nb; i += 256) lhist[i] = 0;
  __syncthreads();
  int base = blockIdx.x * CHUNK;
  int lim = min(base + CHUNK, e);
  for (int i = base + t; i < lim; i += 256)
    atomicAdd(&lhist[ei[e + i] >> 8], 1);
  __syncthreads();
  for (int i = t; i < nb; i += 256) {
    int c = lhist[i];
    gbase[i] = c ? atomicAdd(&ccur[i], c) : 0;
    lcur[i] = 0;
  }
  __syncthreads();
  for (int i = base + t; i < lim; i += 256) {
    int d = ei[e + i];
    int s = ei[i];
    int bin = d >> 8;
    int slot = atomicAdd(&lcur[bin], 1);
    bpak[gbase[bin] + slot] = (uint)s | ((uint)(d & 255) << 24);
  }
}

// One block per 256-node tile: counting sort by dstLocal; emits ssrc, off, dinv.
__global__ __launch_bounds__(256) void binsort_k(const uint* __restrict__ bpak,
                                                 const int* __restrict__ cbase,
                                                 float* __restrict__ dinv,
                                                 int* __restrict__ off,
                                                 int* __restrict__ ssrc, int n) {
  __shared__ int hist[256], cur[256], sc[256];
  int b = blockIdx.x, t = threadIdx.x;
  int beg = cbase[b], end = cbase[b + 1];
  hist[t] = 0;
  __syncthreads();
  for (int j = beg + t; j < end; j += 256) atomicAdd(&hist[bpak[j] >> 24], 1);
  __syncthreads();
  int cnt = hist[t];
  sc[t] = cnt;
  __syncthreads();
  for (int d = 1; d < 256; d <<= 1) {
    int x = (t >= d) ? sc[t - d] : 0;
    __syncthreads();
    sc[t] += x;
    __syncthreads();
  }
  int excl = sc[t] - cnt;
  cur[t] = excl;
  int node = b * 256 + t;
  if (node < n) {
    dinv[node] = rsqrtf((float)cnt + 1.0f);
    off[node] = beg + excl;
  }
  __syncthreads();
  for (int j = beg + t; j < end; j += 256) {
    uint pak = bpak[j];
    int pos = atomicAdd(&cur[pak >> 24], 1);
    ssrc[beg + pos] = (int)(pak & 0xFFFFFFu);
  }
}

// ---------------- W^T cast (3 matrices, 128x128 each) ----------------
__global__ __launch_bounds__(256) void wtcast_k(const float* __restrict__ W1,
                                                const float* __restrict__ W2,
                                                const float* __restrict__ W3,
                                                ushort* __restrict__ Wt1,
                                                ushort* __restrict__ Wt2,
                                                ushort* __restrict__ Wt3) {
  int b = blockIdx.x;
  const float* W = (b < 64) ? W1 : ((b < 128) ? W2 : W3);
  ushort* Wt = (b < 64) ? Wt1 : ((b < 128) ? Wt2 : Wt3);
  int idx = (b & 63) * 256 + threadIdx.x;   // idx = n*128 + k
  int nn = idx >> 7, kk = idx & 127;
  Wt[idx] = f2bf(W[kk * 128 + nn]);
}

// ---------------- MFMA GEMM: 1 wave = 16 rows x 128 cols, Wt in LDS ----------------
// A-frag (16x16x32 bf16): lane l holds A[row = l&15][k = (l>>4)*8 + j], j=0..7
// B-frag:                 lane l holds B[k = (l>>4)*8 + j][col = l&15]  (from Wt[col][k])
// C/D:                    lane l, reg j -> (row = (l>>4)*4 + j, col = l&15)   [m89]
// LDS layout: 16B slots, slot' = slot ^ (row & 15)  -> column reads are 2-way = free.
template <int EPI>
__global__ __launch_bounds__(256) void gemm_g(
    const void* __restrict__ inv_, const ushort* __restrict__ Wt,
    const float* __restrict__ dinv, const float* __restrict__ bias,
    ushort* __restrict__ outA, int n)
{
  __shared__ ushort sWt[128 * 128];   // 32 KB
  const int t = threadIdx.x;

  // cooperative swizzled stage of Wt
  {
    const uint4* W4 = (const uint4*)Wt;
    uint4* S4 = (uint4*)sWt;
    #pragma unroll
    for (int j = 0; j < 8; ++j) {
      int idx = t + j * 256;                 // 0..2047 16B-slots
      int row = idx >> 4, slot = idx & 15;
      S4[(row << 4) | (slot ^ (row & 15))] = W4[idx];
    }
  }
  __syncthreads();   // single barrier; all waves participate before any exit

  const int wid = t >> 6, lane = t & 63;
  const int rbase = blockIdx.x * 64 + wid * 16;
  if (rbase >= n) return;

  const int l16 = lane & 15, kc = lane >> 4, k0 = kc * 8;
  int arow = rbase + l16;
  bool rok = arow < n;
  int arow_c = rok ? arow : (n - 1);

  bf16x8 afr[4];
  if constexpr (EPI) {
    const ushort* in = (const ushort*)inv_;
    float dv = dinv[arow_c];
    #pragma unroll
    for (int kk = 0; kk < 4; ++kk) {
      uint4 r4 = *(const uint4*)(in + (size_t)arow_c * 128 + kk * 32 + k0);
      float4 bb0 = *(const float4*)(bias + kk * 32 + k0);
      float4 bb1 = *(const float4*)(bias + kk * 32 + k0 + 4);
      uint rr[4] = {r4.x, r4.y, r4.z, r4.w};
      float bb[8] = {bb0.x, bb0.y, bb0.z, bb0.w, bb1.x, bb1.y, bb1.z, bb1.w};
      bf16x8 a;
      #pragma unroll
      for (int q = 0; q < 4; ++q) {
        float lo = fmaxf(fmaf(dv, bflo(rr[q]), bb[2 * q]), 0.f);
        float hi = fmaxf(fmaf(dv, bfhi(rr[q]), bb[2 * q + 1]), 0.f);
        a[2 * q]     = (short)f2bf(lo);
        a[2 * q + 1] = (short)f2bf(hi);
      }
      afr[kk] = rok ? a : (bf16x8)0;
    }
  } else {
    const float4* in4 = (const float4*)inv_;
    #pragma unroll
    for (int kk = 0; kk < 4; ++kk) {
      float4 p0 = in4[(size_t)arow_c * 32 + kk * 8 + kc * 2];
      float4 p1 = in4[(size_t)arow_c * 32 + kk * 8 + kc * 2 + 1];
      float f[8] = {p0.x, p0.y, p0.z, p0.w, p1.x, p1.y, p1.z, p1.w};
      bf16x8 a;
      #pragma unroll
      for (int q = 0; q < 8; ++q) a[q] = (short)f2bf(f[q]);
      afr[kk] = rok ? a : (bf16x8)0;
    }
  }

  f32x4 acc[8];
  #pragma unroll
  for (int nt = 0; nt < 8; ++nt) acc[nt] = (f32x4){0.f, 0.f, 0.f, 0.f};

  #pragma unroll
  for (int kk = 0; kk < 4; ++kk) {
    #pragma unroll
    for (int nt = 0; nt < 8; ++nt) {
      int brow = nt * 16 + l16;
      int bslot = kk * 4 + kc;
      bf16x8 bfr = *(const bf16x8*)(sWt + (((brow << 4) | (bslot ^ (brow & 15))) << 3));
      acc[nt] = __builtin_amdgcn_mfma_f32_16x16x32_bf16(afr[kk], bfr, acc[nt], 0, 0, 0);
    }
  }

  // epilogue: g = dinv[row] * acc -> bf16 store
  float dvr[4];
  int rr[4];
  #pragma unroll
  for (int j = 0; j < 4; ++j) {
    rr[j] = rbase + kc * 4 + j;
    dvr[j] = (rr[j] < n) ? dinv[rr[j]] : 0.f;
  }
  #pragma unroll
  for (int nt = 0; nt < 8; ++nt) {
    int col = nt * 16 + l16;
    #pragma unroll
    for (int j = 0; j < 4; ++j) {
      if (rr[j] < n)
        outA[(size_t)rr[j] * 128 + col] = f2bf(acc[nt][j] * dvr[j]);
    }
  }
}

// ---------------- gather: 1 wave per dst node, bf16 rows, 8-deep pipeline ----------------
__global__ __launch_bounds__(256) void gather_k(const uint* __restrict__ A,
                                                uint* __restrict__ B,
                                                const int* __restrict__ ssrc,
                                                const int* __restrict__ off, int n) {
  int w = (blockIdx.x * 256 + threadIdx.x) >> 6;
  int lane = threadIdx.x & 63;
  if (w >= n) return;
  int beg = off[w], end = off[w + 1];
  uint sv = A[(size_t)w * 64 + lane];        // self-loop term g[i]
  float ax = bflo(sv), ay = bfhi(sv);
  int j = beg;
  for (; j + 8 <= end; j += 8) {
    uint v0 = A[(size_t)ssrc[j + 0] * 64 + lane];
    uint v1 = A[(size_t)ssrc[j + 1] * 64 + lane];
    uint v2 = A[(size_t)ssrc[j + 2] * 64 + lane];
    uint v3 = A[(size_t)ssrc[j + 3] * 64 + lane];
    uint v4 = A[(size_t)ssrc[j + 4] * 64 + lane];
    uint v5 = A[(size_t)ssrc[j + 5] * 64 + lane];
    uint v6 = A[(size_t)ssrc[j + 6] * 64 + lane];
    uint v7 = A[(size_t)ssrc[j + 7] * 64 + lane];
    ax += ((bflo(v0) + bflo(v1)) + (bflo(v2) + bflo(v3))) +
          ((bflo(v4) + bflo(v5)) + (bflo(v6) + bflo(v7)));
    ay += ((bfhi(v0) + bfhi(v1)) + (bfhi(v2) + bfhi(v3))) +
          ((bfhi(v4) + bfhi(v5)) + (bfhi(v6) + bfhi(v7)));
  }
  for (; j + 4 <= end; j += 4) {
    uint v0 = A[(size_t)ssrc[j + 0] * 64 + lane];
    uint v1 = A[(size_t)ssrc[j + 1] * 64 + lane];
    uint v2 = A[(size_t)ssrc[j + 2] * 64 + lane];
    uint v3 = A[(size_t)ssrc[j + 3] * 64 + lane];
    ax += (bflo(v0) + bflo(v1)) + (bflo(v2) + bflo(v3));
    ay += (bfhi(v0) + bfhi(v1)) + (bfhi(v2) + bfhi(v3));
  }
  for (; j < end; ++j) {
    uint v = A[(size_t)ssrc[j] * 64 + lane];
    ax += bflo(v); ay += bfhi(v);
  }
  B[(size_t)w * 64 + lane] = packbf(ax, ay);
}

// ---------------- mean: partials then reduce ----------------
__global__ __launch_bounds__(256) void mean1_k(const uint* __restrict__ B,
                                               const float* __restrict__ dinv,
                                               const float* __restrict__ bias,
                                               float* __restrict__ part, int n) {
  __shared__ float s[512];
  int t = threadIdx.x, cg = t & 63, rg = t >> 6;
  float bx = bias[cg * 2], by = bias[cg * 2 + 1];
  float sx = 0.f, sy = 0.f;
  for (int row = blockIdx.x * 4 + rg; row < n; row += 1024) {
    uint v = B[(size_t)row * 64 + cg];
    float dv = dinv[row];
    sx += fmaxf(fmaf(dv, bflo(v), bx), 0.f);
    sy += fmaxf(fmaf(dv, bfhi(v), by), 0.f);
  }
  s[t * 2] = sx; s[t * 2 + 1] = sy;
  __syncthreads();
  if (t < 64) {
    float rx = s[t * 2] + s[(t + 64) * 2] + s[(t + 128) * 2] + s[(t + 192) * 2];
    float ry = s[t * 2 + 1] + s[(t + 64) * 2 + 1] + s[(t + 128) * 2 + 1] + s[(t + 192) * 2 + 1];
    part[blockIdx.x * 128 + cg * 2] = rx;
    part[blockIdx.x * 128 + cg * 2 + 1] = ry;
  }
}

__global__ __launch_bounds__(128) void mean2_k(const float* __restrict__ part,
                                               float* __restrict__ out, float invn) {
  int c = threadIdx.x;
  float s = 0.f;
  for (int b = 0; b < 256; ++b) s += part[b * 128 + c];
  out[c] = s * invn;
}

extern "C" void kernel_launch(void* const* d_in, const int* in_sizes, int n_in,
                              void* d_out, int out_size, void* d_ws, size_t ws_size,
                              hipStream_t stream) {
  const float* x  = (const float*)d_in[0];
  const int*   ei = (const int*)d_in[1];
  const float* W1 = (const float*)d_in[2];
  const float* b1 = (const float*)d_in[3];
  const float* W2 = (const float*)d_in[4];
  const float* b2 = (const float*)d_in[5];
  const float* W3 = (const float*)d_in[6];
  const float* b3 = (const float*)d_in[7];
  float* out = (float*)d_out;

  const int n = in_sizes[0] / 128;
  const int e = in_sizes[1] / 2;
  const int nb = (n + 255) / 256;          // 256-node tiles (nb <= 512)
  const int nchunk = (e + CHUNK - 1) / CHUNK;

  char* p = (char*)d_ws;
  auto alloc = [&](size_t bytes) {
    char* r = p;
    p += (bytes + 255) & ~(size_t)255;
    return r;
  };
  int*    cnt   = (int*)alloc((size_t)nb * 4);
  int*    cbase = (int*)alloc((size_t)(nb + 1) * 4);
  int*    ccur  = (int*)alloc((size_t)nb * 4);
  int*    off   = (int*)alloc((size_t)(n + 1) * 4);
  float*  dinv  = (float*)alloc((size_t)n * 4);
  uint*   bpak  = (uint*)alloc((size_t)e * 4);
  int*    ssrc  = (int*)alloc((size_t)e * 4);
  ushort* Wt1   = (ushort*)alloc(128 * 128 * 2);
  ushort* Wt2   = (ushort*)alloc(128 * 128 * 2);
  ushort* Wt3   = (ushort*)alloc(128 * 128 * 2);
  ushort* bufA  = (ushort*)alloc((size_t)n * 128 * 2);
  ushort* bufB  = (ushort*)alloc((size_t)n * 128 * 2);
  float*  part  = (float*)alloc(256 * 128 * 4);

  // CSR build (tile-binned) + dinv + Wt
  hipMemsetAsync(cnt, 0, (size_t)nb * 4, stream);
  chist_k     <<<nchunk, 256, 0, stream>>>(ei, cnt, e, nb);
  cscan_k     <<<1, 512, 0, stream>>>(cnt, cbase, ccur, off, nb, n, e);
  binscatter_k<<<nchunk, 256, 0, stream>>>(ei, ccur, bpak, e, nb);
  binsort_k   <<<nb, 256, 0, stream>>>(bpak, cbase, dinv, off, ssrc, n);
  wtcast_k    <<<192, 256, 0, stream>>>(W1, W2, W3, Wt1, Wt2, Wt3);

  const int gb = (n + 63) / 64;
  const int ab = (n * 64 + 255) / 256;

  gemm_g<0><<<gb, 256, 0, stream>>>(x, Wt1, dinv, nullptr, bufA, n);
  gather_k <<<ab, 256, 0, stream>>>((const uint*)bufA, (uint*)bufB, ssrc, off, n);
  gemm_g<1><<<gb, 256, 0, stream>>>(bufB, Wt2, dinv, b1, bufA, n);
  gather_k <<<ab, 256, 0, stream>>>((const uint*)bufA, (uint*)bufB, ssrc, off, n);
  gemm_g<1><<<gb, 256, 0, stream>>>(bufB, Wt3, dinv, b2, bufA, n);
  gather_k <<<ab, 256, 0, stream>>>((const uint*)bufA, (uint*)bufB, ssrc, off, n);

  mean1_k<<<256, 256, 0, stream>>>((const uint*)bufB, dinv, b3, part, n);
  mean2_k<<<1, 128, 0, stream>>>(part, out, 1.0f / (float)n);
}